// Round 12
// baseline (304.482 us; speedup 1.0000x reference)
//
#include <hip/hip_runtime.h>
#include <math.h>

#define B_DIM 4096
#define T_DIM 1024
#define NCLS  3

#define NT (T_DIM / 64)        // 16 t-chunks (64 t per block, lane = t)
#define ROWS 8                 // b-rows per thread
#define WAVES 4                // waves per block
#define NBC (B_DIM / (WAVES * ROWS))  // 128 b-chunks -> grid 2048
#define THREADS 256
#define LN2 0.69314718055994531f
#define WS_FLOATS (T_DIM * NCLS * 2)   // gcnt + gksum
#define GRID (NT * NBC)

__device__ __forceinline__ float rcpf(float x) { return __builtin_amdgcn_rcpf(x); }

__global__ void kl_zero(float* ws) {
    int i = blockIdx.x * 256 + threadIdx.x;
    if (i < WS_FLOATS + 1) ws[i] = 0.0f;   // +1: done-counter (bits zeroed)
}

__global__ __launch_bounds__(THREADS)
void kl_fused(const float* __restrict__ logits,
              const float* __restrict__ targets,
              float* __restrict__ gcnt,
              float* __restrict__ gksum,
              unsigned int* __restrict__ done,
              float* __restrict__ out) {
    const int tchunk = blockIdx.x % NT;
    const int bchunk = blockIdx.x / NT;
    const int lane = threadIdx.x & 63;
    const int wv   = threadIdx.x >> 6;            // 0..3
    const int t    = tchunk * 64 + lane;
    const int b0   = bchunk * (WAVES * ROWS) + wv * ROWS;

    float k0 = 0.f, k1 = 0.f, k2 = 0.f;
    float n0 = 0.f, n1 = 0.f, n2 = 0.f;

    const size_t row0 = (size_t)b0 * T_DIM + t;
    const float* tgp = targets + row0 * 3;
    const float* lgp = logits + row0 * 2;

    float3 tg = *(const float3*)tgp;
    float2 lg = *(const float2*)lgp;

#pragma unroll
    for (int it = 0; it < ROWS; ++it) {
        float3 tgc = tg;
        float2 lgc = lg;
        if (it < ROWS - 1) {                       // prefetch next row
            tg = *(const float3*)(tgp + (size_t)(it + 1) * T_DIM * 3);
            lg = *(const float2*)(lgp + (size_t)(it + 1) * T_DIM * 2);
        }

        // branchless sanitize (padding rows are all -inf; valid tc in [5,30])
        const bool v = (tgc.y > 0.0f);
        const float vm  = v ? 1.0f : 0.0f;
        const float tw  = v ? tgc.x : 0.5f;
        const float tc  = v ? tgc.y : 5.0f;
        const float dxs = v ? tgc.z : 0.0f;

        // predictions
        const float pw = rcpf(1.0f + __expf(-lgc.x));
        const float pc = fmaf(rcpf(1.0f + __expf(-lgc.y)), (float)(T_DIM - 1), 5.0f);

        // Beta params
        const float ta = fmaf(tc, tw, 1.0f);
        const float tb = tc - tc * tw + 1.0f;
        const float pa = fmaf(pc, pw, 1.0f);
        const float pb = pc - pc * pw + 1.0f;
        const float sp = tc + 2.0f;               // ta+tb, >= 7
        const float sq = pc + 2.0f;               // pa+pb, >= 7

        // shifted args: Stirling needs >=2, digamma >=3
        const float yta = ta + 2.0f, ytb = tb + 2.0f;
        const float ypa = pa + 1.0f, ypb = pb + 1.0f;

        const float u_ta = rcpf(yta), u_tb = rcpf(ytb);
        const float u_pa = rcpf(ypa), u_pb = rcpf(ypb);
        const float u_sp = rcpf(sp),  u_sq = rcpf(sq);
        const float qta = ta * (ta + 1.0f);       // gamma-shift for ta by 2
        const float qtb = tb * (tb + 1.0f);
        const float rqta = rcpf(qta), rqtb = rcpf(qtb);

        // ---- folded log2 part ----
        // L = (pa+.5)lg2(ypa/yta) + (pb+.5)lg2(ypb/ytb) + (sq-.5)lg2(sp/sq)
        //   + lg2( qta*qtb / (pa*pb*yta*ytb) )
        const float lr_a = __log2f(ypa * u_ta);
        const float lr_b = __log2f(ypb * u_tb);
        const float lr_s = __log2f(sp * u_sq);
        const float lr_c = __log2f(qta * qtb * rcpf(pa * pb * yta * ytb));
        float L = fmaf(pa + 0.5f, lr_a,
                  fmaf(pb + 0.5f, lr_b,
                  fmaf(sq - 0.5f, lr_s, lr_c)));

        // ---- non-log remainder ----
        // Stirling u/12 sum (signs: +ypa +ypb +sp -yta -ytb -sq); -y terms sum to +2
        const float S = (u_pa + u_pb + u_sp) - (u_ta + u_tb + u_sq);

        // digamma remainders: r(y) = -u/2 - u^2*(c1 - u^2*(c2 - u^2*c3))
        #define DGR(u) (-0.5f*(u) - (u)*(u)*(0.083333333333333f \
                        - (u)*(u)*(0.0083333333333333f - (u)*(u)*0.0039682539682540f)))
        const float rta = DGR(u_ta) - (2.0f * ta + 1.0f) * rqta;  // psi(ta) shift by 2
        const float rtb = DGR(u_tb) - (2.0f * tb + 1.0f) * rqtb;
        const float rsp = DGR(u_sp);
        #undef DGR

        float kl = fmaf(LN2, L, 2.0f) + S * 0.083333333333333f
                 + (ta - pa) * rta + (tb - pb) * rtb + (sq - sp) * rsp;

        // class masks (dx is exactly 0.0/1.0/2.0)
        const float m1 = (dxs == 1.0f) ? vm : 0.0f;
        const float m2 = (dxs == 2.0f) ? vm : 0.0f;
        const float m0 = vm - m1 - m2;
        k0 = fmaf(m0, kl, k0);  n0 += m0;
        k1 = fmaf(m1, kl, k1);  n1 += m1;
        k2 = fmaf(m2, kl, k2);  n2 += m2;
    }

    // block reduction: 4 waves share the same 64 t values
    __shared__ float rk[WAVES][64][NCLS];
    __shared__ float rn[WAVES][64][NCLS];
    __shared__ int last;
    rk[wv][lane][0] = k0; rk[wv][lane][1] = k1; rk[wv][lane][2] = k2;
    rn[wv][lane][0] = n0; rn[wv][lane][1] = n1; rn[wv][lane][2] = n2;
    __syncthreads();

    if (threadIdx.x < 64) {
        const int l = threadIdx.x;
        const int gt = tchunk * 64 + l;
#pragma unroll
        for (int c = 0; c < NCLS; ++c) {
            float ks = rk[0][l][c] + rk[1][l][c] + rk[2][l][c] + rk[3][l][c];
            float ns = rn[0][l][c] + rn[1][l][c] + rn[2][l][c] + rn[3][l][c];
            atomicAdd(&gksum[gt * NCLS + c], ks);
            atomicAdd(&gcnt[gt * NCLS + c], ns);
        }
    }

    // ---- last-block ticket: the final block performs the global reduce ----
    __threadfence();                 // make this block's atomics device-visible
    __syncthreads();
    if (threadIdx.x == 0)
        last = (atomicAdd(done, 1u) == (unsigned)(GRID - 1));
    __syncthreads();

    if (last) {
        __threadfence();             // acquire: see all blocks' histograms
        float s = 0.0f;
        for (int i = threadIdx.x; i < T_DIM * NCLS; i += THREADS) {
            float cv = gcnt[i];
            if (cv > 0.0f) s += gksum[i] * rcpf(cv);
        }
        // reuse rk as reduction scratch
        ((float*)rk)[threadIdx.x] = s;
        __syncthreads();
        for (int off = THREADS / 2; off > 0; off >>= 1) {
            if ((int)threadIdx.x < off)
                ((float*)rk)[threadIdx.x] += ((float*)rk)[threadIdx.x + off];
            __syncthreads();
        }
        if (threadIdx.x == 0) out[0] = ((float*)rk)[0] / (float)(NCLS * T_DIM);
    }
}

extern "C" void kernel_launch(void* const* d_in, const int* in_sizes, int n_in,
                              void* d_out, int out_size, void* d_ws, size_t ws_size,
                              hipStream_t stream) {
    const float* logits  = (const float*)d_in[0];  // [B,T,2] f32
    const float* targets = (const float*)d_in[1];  // [B,T,3] f32
    float* gcnt  = (float*)d_ws;                   // [T*3]
    float* gksum = gcnt + T_DIM * NCLS;            // [T*3]
    unsigned int* done = (unsigned int*)(gksum + T_DIM * NCLS);
    float* out   = (float*)d_out;

    kl_zero<<<(WS_FLOATS + 1 + 255) / 256, 256, 0, stream>>>((float*)d_ws);
    kl_fused<<<GRID, THREADS, 0, stream>>>(logits, targets, gcnt, gksum, done, out);
}

// Round 14
// 112.931 us; speedup vs baseline: 2.6962x; 2.6962x over previous
//
#include <hip/hip_runtime.h>
#include <math.h>

#define B_DIM 4096
#define T_DIM 1024
#define NCLS  3

#define NT (T_DIM / 64)        // 16 t-chunks (64 t per block, lane = t)
#define ROWS 8                 // b-rows per thread
#define WAVES 4                // waves per block
#define NBC (B_DIM / (WAVES * ROWS))  // 128 b-chunks -> grid 2048
#define THREADS 256
#define LN2 0.69314718055994531f

__device__ __forceinline__ float rcpf(float x) { return __builtin_amdgcn_rcpf(x); }

__global__ void kl_zero(float* ws) {
    int i = blockIdx.x * 256 + threadIdx.x;
    if (i < T_DIM * NCLS * 2) ws[i] = 0.0f;
}

__global__ __launch_bounds__(THREADS)
void kl_partial(const float* __restrict__ logits,
                const float* __restrict__ targets,
                float* __restrict__ gcnt,
                float* __restrict__ gksum) {
    const int tchunk = blockIdx.x % NT;
    const int bchunk = blockIdx.x / NT;
    const int lane = threadIdx.x & 63;
    const int wv   = threadIdx.x >> 6;            // 0..3
    const int t    = tchunk * 64 + lane;
    const int b0   = bchunk * (WAVES * ROWS) + wv * ROWS;

    float k0 = 0.f, k1 = 0.f, k2 = 0.f;
    float n0 = 0.f, n1 = 0.f, n2 = 0.f;

    const size_t row0 = (size_t)b0 * T_DIM + t;
    const float* tgp = targets + row0 * 3;
    const float* lgp = logits + row0 * 2;

    float3 tg = *(const float3*)tgp;
    float2 lg = *(const float2*)lgp;

#pragma unroll
    for (int it = 0; it < ROWS; ++it) {
        float3 tgc = tg;
        float2 lgc = lg;
        if (it < ROWS - 1) {                       // prefetch next row
            tg = *(const float3*)(tgp + (size_t)(it + 1) * T_DIM * 3);
            lg = *(const float2*)(lgp + (size_t)(it + 1) * T_DIM * 2);
        }

        // validity: padding rows are all -inf; valid tc in [5,30].
        // lane = t, all lanes share b -> valid t is a prefix of the chunk;
        // ~24% of (b,chunk) waves are fully invalid: uniform skip.
        const bool v = (tgc.y > 0.0f);
        if (!__any(v)) continue;

        const float vm  = v ? 1.0f : 0.0f;
        const float tw  = v ? tgc.x : 0.5f;
        const float tc  = v ? tgc.y : 5.0f;
        const float dxs = v ? tgc.z : 0.0f;

        // predictions
        const float pw = rcpf(1.0f + __expf(-lgc.x));
        const float pc = fmaf(rcpf(1.0f + __expf(-lgc.y)), (float)(T_DIM - 1), 5.0f);

        // Beta params
        const float ta = fmaf(tc, tw, 1.0f);
        const float tb = tc - tc * tw + 1.0f;
        const float pa = fmaf(pc, pw, 1.0f);
        const float pb = pc - pc * pw + 1.0f;
        const float sp = tc + 2.0f;               // ta+tb, >= 7
        const float sq = pc + 2.0f;               // pa+pb, >= 7

        // shifted args: Stirling needs >=2, digamma >=3
        const float yta = ta + 2.0f, ytb = tb + 2.0f;
        const float ypa = pa + 1.0f, ypb = pb + 1.0f;

        const float u_ta = rcpf(yta), u_tb = rcpf(ytb);
        const float u_sp = rcpf(sp),  u_sq = rcpf(sq);
        // u_pa + u_pb in ONE rcp: (ypa+ypb) / (ypa*ypb), ypa+ypb = sq+2
        const float upab = (sq + 2.0f) * rcpf(ypa * ypb);
        const float qta = ta * (ta + 1.0f);       // gamma-shift for ta by 2
        const float qtb = tb * (tb + 1.0f);
        const float rqta = rcpf(qta), rqtb = rcpf(qtb);

        // ---- folded log2 part ----
        // L = (pa+.5)lg2(ypa/yta) + (pb+.5)lg2(ypb/ytb) + (sq-.5)lg2(sp/sq)
        //   + lg2( qta*qtb / (pa*pb*yta*ytb) )
        const float lr_a = __log2f(ypa * u_ta);
        const float lr_b = __log2f(ypb * u_tb);
        const float lr_s = __log2f(sp * u_sq);
        const float lr_c = __log2f(qta * qtb * rcpf(pa * pb * yta * ytb));
        float L = fmaf(pa + 0.5f, lr_a,
                  fmaf(pb + 0.5f, lr_b,
                  fmaf(sq - 0.5f, lr_s, lr_c)));

        // ---- non-log remainder ----
        // Stirling u/12 sum (signs: +ypa +ypb +sp -yta -ytb -sq); -y terms sum to +2
        const float S = (upab + u_sp) - (u_ta + u_tb + u_sq);

        // digamma remainders: r(y) = -u/2 - u^2*(c1 - u^2*(c2 - u^2*c3))
        #define DGR(u) (-0.5f*(u) - (u)*(u)*(0.083333333333333f \
                        - (u)*(u)*(0.0083333333333333f - (u)*(u)*0.0039682539682540f)))
        const float rta = DGR(u_ta) - (2.0f * ta + 1.0f) * rqta;  // psi(ta) shift by 2
        const float rtb = DGR(u_tb) - (2.0f * tb + 1.0f) * rqtb;
        const float rsp = DGR(u_sp);
        #undef DGR

        float kl = fmaf(LN2, L, 2.0f) + S * 0.083333333333333f
                 + (ta - pa) * rta + (tb - pb) * rtb + (sq - sp) * rsp;

        // class masks (dx is exactly 0.0/1.0/2.0)
        const float m1 = (dxs == 1.0f) ? vm : 0.0f;
        const float m2 = (dxs == 2.0f) ? vm : 0.0f;
        const float m0 = vm - m1 - m2;
        k0 = fmaf(m0, kl, k0);  n0 += m0;
        k1 = fmaf(m1, kl, k1);  n1 += m1;
        k2 = fmaf(m2, kl, k2);  n2 += m2;
    }

    // block reduction: 4 waves share the same 64 t values
    __shared__ float rk[WAVES][64][NCLS];
    __shared__ float rn[WAVES][64][NCLS];
    rk[wv][lane][0] = k0; rk[wv][lane][1] = k1; rk[wv][lane][2] = k2;
    rn[wv][lane][0] = n0; rn[wv][lane][1] = n1; rn[wv][lane][2] = n2;
    __syncthreads();

    if (threadIdx.x < 64) {
        const int l = threadIdx.x;
        const int gt = tchunk * 64 + l;
#pragma unroll
        for (int c = 0; c < NCLS; ++c) {
            float ks = rk[0][l][c] + rk[1][l][c] + rk[2][l][c] + rk[3][l][c];
            float ns = rn[0][l][c] + rn[1][l][c] + rn[2][l][c] + rn[3][l][c];
            atomicAdd(&gksum[gt * NCLS + c], ks);
            atomicAdd(&gcnt[gt * NCLS + c], ns);
        }
    }
}

__global__ void kl_final(const float* __restrict__ gcnt,
                         const float* __restrict__ gksum,
                         float* __restrict__ out) {
    __shared__ float red[256];
    float s = 0.0f;
    for (int i = threadIdx.x; i < T_DIM * NCLS; i += 256) {
        float cv = gcnt[i];
        if (cv > 0.0f) s += gksum[i] * rcpf(cv);
    }
    red[threadIdx.x] = s;
    __syncthreads();
    for (int off = 128; off > 0; off >>= 1) {
        if ((int)threadIdx.x < off) red[threadIdx.x] += red[threadIdx.x + off];
        __syncthreads();
    }
    if (threadIdx.x == 0) out[0] = red[0] / (float)(NCLS * T_DIM);
}

extern "C" void kernel_launch(void* const* d_in, const int* in_sizes, int n_in,
                              void* d_out, int out_size, void* d_ws, size_t ws_size,
                              hipStream_t stream) {
    const float* logits  = (const float*)d_in[0];  // [B,T,2] f32
    const float* targets = (const float*)d_in[1];  // [B,T,3] f32
    float* gcnt  = (float*)d_ws;                   // [T*3]
    float* gksum = gcnt + T_DIM * NCLS;            // [T*3]
    float* out   = (float*)d_out;

    kl_zero<<<(T_DIM * NCLS * 2 + 255) / 256, 256, 0, stream>>>((float*)d_ws);
    kl_partial<<<NT * NBC, THREADS, 0, stream>>>(logits, targets, gcnt, gksum);
    kl_final<<<1, 256, 0, stream>>>(gcnt, gksum, out);
}